// Round 9
// baseline (29.921 us; speedup 1.0000x reference)
//
#include <hip/hip_runtime.h>
#include <hip/hip_bf16.h>
#include <math.h>

#define QN 128
#define SN 128
#define HN 32
#define CN (QN * SN)
#define TILE_R 128   // batch rows per block

using half8   = __attribute__((ext_vector_type(8))) _Float16;
using floatx4 = __attribute__((ext_vector_type(4))) float;

// Grouped-GEMM via MFMA, NO LDS, NO barriers. Block: 256 threads (4 waves),
// one q, 128 batch rows; wave w owns rows w*32..w*32+31 (two 16-row M-tiles).
// mfma_f32_16x16x32_f16: A-frag lane(nA=lane&15, koct=lane>>4) holds
// X[row0+nA][kk*32 + koct*8 + i] -> 8 consecutive fp32 = two float4 global
// loads per frag (16 rows x 128B contiguous per instr: fully line-coalesced).
// x has zero intra-block reuse, so the R8 LDS round-trip was pure overhead.
// B-frags: W1[q] gathered once per wave (L1/L2-hot; all blocks of a given q
// land on XCD q%8 since gridDim.x=128). Epilogue identical to passing R8.
__global__ __launch_bounds__(256, 4)
void divenc_kernel(const float* __restrict__ x,
                   const float* __restrict__ W1,
                   const float* __restrict__ b1,
                   const float* __restrict__ W2,
                   const float* __restrict__ b2,
                   float* __restrict__ out) {
  const int q    = blockIdx.x;
  const int b0   = blockIdx.y * TILE_R;
  const int tid  = threadIdx.x;
  const int lane = tid & 63;
  const int wid  = __builtin_amdgcn_readfirstlane(tid >> 6);
  const int nA   = lane & 15;   // n-col / A-row within tile
  const int koct = lane >> 4;   // k-octet 0..3

  // ---- B-frags: lane holds W1[q][kk*32+koct*8+i][n0*16+nA] as fp16.
  const float* __restrict__ w1q = W1 + (size_t)q * (SN * HN);
  half8 bf[2][4];
  #pragma unroll
  for (int n0 = 0; n0 < 2; ++n0) {
    #pragma unroll
    for (int kk = 0; kk < 4; ++kk) {
      #pragma unroll
      for (int i = 0; i < 8; ++i) {
        const int k = kk * 32 + koct * 8 + i;
        bf[n0][kk][i] = (_Float16)w1q[k * HN + n0 * 16 + nA];
      }
    }
  }

  // ---- A-frags direct from global + MFMA
  floatx4 z = {0.f, 0.f, 0.f, 0.f};
  floatx4 acc[2][2];
  acc[0][0] = z; acc[0][1] = z; acc[1][0] = z; acc[1][1] = z;

  const int row0 = b0 + wid * 32;
  #pragma unroll
  for (int mt = 0; mt < 2; ++mt) {
    const float* __restrict__ rp =
        x + (size_t)(row0 + mt * 16 + nA) * CN + q * SN + koct * 8;
    #pragma unroll
    for (int kk = 0; kk < 4; ++kk) {
      const float4 va = *reinterpret_cast<const float4*>(rp + kk * 32);
      const float4 vb = *reinterpret_cast<const float4*>(rp + kk * 32 + 4);
      half8 af;
      af[0] = (_Float16)va.x; af[1] = (_Float16)va.y;
      af[2] = (_Float16)va.z; af[3] = (_Float16)va.w;
      af[4] = (_Float16)vb.x; af[5] = (_Float16)vb.y;
      af[6] = (_Float16)vb.z; af[7] = (_Float16)vb.w;
      acc[mt][0] = __builtin_amdgcn_mfma_f32_16x16x32_f16(af, bf[0][kk], acc[mt][0], 0, 0, 0);
      acc[mt][1] = __builtin_amdgcn_mfma_f32_16x16x32_f16(af, bf[1][kk], acc[mt][1], 0, 0, 0);
    }
  }

  // ---- epilogue. C/D: col = nA, row (within tile) = koct*4 + reg.
  const float b1a = b1[q * HN + nA],  b1b = b1[q * HN + 16 + nA];
  const float w2a = W2[q * HN + nA],  w2b = W2[q * HN + 16 + nA];
  const float b2q = b2[q];

  #pragma unroll
  for (int mt = 0; mt < 2; ++mt) {
    #pragma unroll
    for (int reg = 0; reg < 4; ++reg) {
      float v0 = acc[mt][0][reg] + b1a;
      v0 = v0 > 0.f ? v0 : expm1f(v0);
      float v1 = acc[mt][1][reg] + b1b;
      v1 = v1 > 0.f ? v1 : expm1f(v1);
      float t = fmaf(v0, w2a, v1 * w2b);
      t += __shfl_xor(t, 1);
      t += __shfl_xor(t, 2);
      t += __shfl_xor(t, 4);
      t += __shfl_xor(t, 8);
      if (nA == 0) {
        const int row = row0 + mt * 16 + koct * 4 + reg;
        out[(size_t)row * QN + q] = t + b2q;
      }
    }
  }
}

extern "C" void kernel_launch(void* const* d_in, const int* in_sizes, int n_in,
                              void* d_out, int out_size, void* d_ws, size_t ws_size,
                              hipStream_t stream) {
  const float* x  = (const float*)d_in[0];
  const float* W1 = (const float*)d_in[1];
  const float* b1 = (const float*)d_in[2];
  const float* W2 = (const float*)d_in[3];
  const float* b2 = (const float*)d_in[4];
  float* out = (float*)d_out;

  const int B = in_sizes[0] / CN;  // 2048
  dim3 grid(QN, B / TILE_R);
  divenc_kernel<<<grid, 256, 0, stream>>>(x, W1, b1, W2, b2, out);
}